// Round 1
// baseline (37.808 us; speedup 1.0000x reference)
//
#include <hip/hip_runtime.h>

// ProximityAwareLoss3Class: B=32, S=65536, C=3.
// Decomposition: all serial structure (FSM mode multipliers + nearest-true/pred
// distances) reduces to per-sequence "last event position" max-scans (forward)
// and "next event position" min-scans (backward):
//   tm_i = (lastT2 > lastT1) exclusive;  pm_i = (lastVP2 > lastVP1) exclusive
//   d_prev = pos - last (inclusive); d_next = next - pos (inclusive)
// Distances clamp at 255 (all factors saturate by d>=25).
// K1: per-chunk summaries -> K2: serial cross-chunk combine (tiny)
// -> K3: per-chunk full pass with block scans -> K4: final reduce.

#define S_LEN 65536
#define BATCH 32
#define CHUNK 2048
#define NTHREADS 256
#define PER_THREAD 8            // CHUNK / NTHREADS
#define CHUNKS_PER_SEQ 32       // S_LEN / CHUNK
#define NCHUNK 1024             // BATCH * CHUNKS_PER_SEQ
#define BIGI 0x3FFFFFFF

struct ChunkSum { int mx[6]; int mn[4]; };   // mx: lastT1,T2,P1,P2,VP1,VP2  mn: firstT1,T2,P1,P2
struct ChunkIn  { int inLast[6]; int inNext[4]; };

// ws layout (bytes)
#define WS_SUMS  0
#define WS_INS   (NCHUNK * (int)sizeof(ChunkSum))            // 40960
#define WS_FLAGS (WS_INS + NCHUNK * (int)sizeof(ChunkIn))    // 81920
#define WS_PART  (WS_FLAGS + BATCH * 4 * 4)                  // 82432 (8-aligned)
// total = WS_PART + NCHUNK*2*8 = 98816 bytes

__device__ __forceinline__ int argmax3(float l0, float l1, float l2) {
    int p = 0; float b = l0;
    if (l1 > b) { p = 1; b = l1; }
    if (l2 > b) { p = 2; }
    return p;
}

__device__ __forceinline__ float ce_of(float l0, float l1, float l2, int lab) {
    if (lab < 0) return 0.0f;                       // ignore_index -100
    float mx = fmaxf(l0, fmaxf(l1, l2));
    float lse = mx + logf(expf(l0 - mx) + expf(l1 - mx) + expf(l2 - mx));
    float ly = (lab == 0) ? l0 : ((lab == 1) ? l1 : l2);
    float w  = (lab == 0) ? 1.0f : 30.0f;           // class_weights [1,30,30]
    return -(ly - lse) * w;
}

__global__ __launch_bounds__(NTHREADS) void k1_summ(const float* __restrict__ logits,
                                                    const int* __restrict__ labels,
                                                    ChunkSum* __restrict__ sums) {
    const int chunkId = blockIdx.x;
    const int seq = chunkId / CHUNKS_PER_SEQ;
    const int cs  = chunkId % CHUNKS_PER_SEQ;
    const int tid = threadIdx.x;
    const int posBase = cs * CHUNK + tid * PER_THREAD;   // sequence-local position
    const int e0 = seq * S_LEN + posBase;

    int lab[PER_THREAD];
    {
        const int4* lp = (const int4*)(labels + e0);
        int4 a = lp[0], b = lp[1];
        lab[0]=a.x; lab[1]=a.y; lab[2]=a.z; lab[3]=a.w;
        lab[4]=b.x; lab[5]=b.y; lab[6]=b.z; lab[7]=b.w;
    }
    float f[3 * PER_THREAD];
    {
        const float4* fp = (const float4*)(logits + 3ll * e0);
        #pragma unroll
        for (int i = 0; i < 6; ++i) {
            float4 v = fp[i];
            f[4*i+0]=v.x; f[4*i+1]=v.y; f[4*i+2]=v.z; f[4*i+3]=v.w;
        }
    }
    int mx[6] = {-1,-1,-1,-1,-1,-1};
    int mn[4] = {BIGI,BIGI,BIGI,BIGI};
    #pragma unroll
    for (int j = 0; j < PER_THREAD; ++j) {
        const int l = lab[j];
        const int p = argmax3(f[3*j], f[3*j+1], f[3*j+2]);
        const int pos = posBase + j;
        if (l == 1) { mx[0] = pos; mn[0] = min(mn[0], pos); }
        if (l == 2) { mx[1] = pos; mn[1] = min(mn[1], pos); }
        if (p == 1) { mx[2] = pos; mn[2] = min(mn[2], pos); }
        if (p == 2) { mx[3] = pos; mn[3] = min(mn[3], pos); }
        const bool valid = (l >= 0);
        if (valid && p == 1) mx[4] = pos;
        if (valid && p == 2) mx[5] = pos;
    }
    __shared__ int sF[6][NTHREADS];
    __shared__ int sB[4][NTHREADS];
    #pragma unroll
    for (int i = 0; i < 6; ++i) sF[i][tid] = mx[i];
    #pragma unroll
    for (int i = 0; i < 4; ++i) sB[i][tid] = mn[i];
    __syncthreads();
    for (int st = NTHREADS / 2; st > 0; st >>= 1) {
        if (tid < st) {
            #pragma unroll
            for (int i = 0; i < 6; ++i) sF[i][tid] = max(sF[i][tid], sF[i][tid + st]);
            #pragma unroll
            for (int i = 0; i < 4; ++i) sB[i][tid] = min(sB[i][tid], sB[i][tid + st]);
        }
        __syncthreads();
    }
    if (tid == 0) {
        ChunkSum out;
        #pragma unroll
        for (int i = 0; i < 6; ++i) out.mx[i] = sF[i][0];
        #pragma unroll
        for (int i = 0; i < 4; ++i) out.mn[i] = sB[i][0];
        sums[chunkId] = out;
    }
}

__global__ __launch_bounds__(64) void k2_combine(const ChunkSum* __restrict__ sums,
                                                 ChunkIn* __restrict__ ins,
                                                 int* __restrict__ anyFlags) {
    const int s = threadIdx.x;
    if (s >= BATCH) return;
    int run[6] = {-1,-1,-1,-1,-1,-1};
    for (int k = 0; k < CHUNKS_PER_SEQ; ++k) {
        const int c = s * CHUNKS_PER_SEQ + k;
        #pragma unroll
        for (int i = 0; i < 6; ++i) ins[c].inLast[i] = run[i];
        #pragma unroll
        for (int i = 0; i < 6; ++i) run[i] = max(run[i], sums[c].mx[i]);
    }
    anyFlags[4*s+0] = (run[0] >= 0) ? 1 : 0;   // any true class1
    anyFlags[4*s+1] = (run[1] >= 0) ? 1 : 0;   // any true class2
    anyFlags[4*s+2] = (run[2] >= 0) ? 1 : 0;   // any pred class1
    anyFlags[4*s+3] = (run[3] >= 0) ? 1 : 0;   // any pred class2
    int rn[4] = {BIGI,BIGI,BIGI,BIGI};
    for (int k = CHUNKS_PER_SEQ - 1; k >= 0; --k) {
        const int c = s * CHUNKS_PER_SEQ + k;
        #pragma unroll
        for (int i = 0; i < 4; ++i) ins[c].inNext[i] = rn[i];
        #pragma unroll
        for (int i = 0; i < 4; ++i) rn[i] = min(rn[i], sums[c].mn[i]);
    }
}

__global__ __launch_bounds__(NTHREADS) void k3_main(const float* __restrict__ logits,
                                                    const int* __restrict__ labels,
                                                    const ChunkIn* __restrict__ ins,
                                                    const int* __restrict__ anyFlags,
                                                    double* __restrict__ partials) {
    const int chunkId = blockIdx.x;
    const int seq = chunkId / CHUNKS_PER_SEQ;
    const int cs  = chunkId % CHUNKS_PER_SEQ;
    const int tid = threadIdx.x;
    const int posBase = cs * CHUNK + tid * PER_THREAD;
    const int e0 = seq * S_LEN + posBase;

    int lab[PER_THREAD]; int prd[PER_THREAD]; float ce[PER_THREAD];
    {
        const int4* lp = (const int4*)(labels + e0);
        int4 a = lp[0], b = lp[1];
        lab[0]=a.x; lab[1]=a.y; lab[2]=a.z; lab[3]=a.w;
        lab[4]=b.x; lab[5]=b.y; lab[6]=b.z; lab[7]=b.w;
    }
    {
        float f[3 * PER_THREAD];
        const float4* fp = (const float4*)(logits + 3ll * e0);
        #pragma unroll
        for (int i = 0; i < 6; ++i) {
            float4 v = fp[i];
            f[4*i+0]=v.x; f[4*i+1]=v.y; f[4*i+2]=v.z; f[4*i+3]=v.w;
        }
        #pragma unroll
        for (int j = 0; j < PER_THREAD; ++j) {
            prd[j] = argmax3(f[3*j], f[3*j+1], f[3*j+2]);
            ce[j]  = ce_of(f[3*j], f[3*j+1], f[3*j+2], lab[j]);
        }
    }

    // thread-local scan summaries
    int lmx[6] = {-1,-1,-1,-1,-1,-1};
    int lmn[4] = {BIGI,BIGI,BIGI,BIGI};
    #pragma unroll
    for (int j = 0; j < PER_THREAD; ++j) {
        const int pos = posBase + j;
        const int l = lab[j], p = prd[j];
        if (l == 1) lmx[0] = pos;
        if (l == 2) lmx[1] = pos;
        if (p == 1) lmx[2] = pos;
        if (p == 2) lmx[3] = pos;
        const bool valid = (l >= 0);
        if (valid && p == 1) lmx[4] = pos;
        if (valid && p == 2) lmx[5] = pos;
    }
    #pragma unroll
    for (int j = PER_THREAD - 1; j >= 0; --j) {
        const int pos = posBase + j;
        const int l = lab[j], p = prd[j];
        if (l == 1) lmn[0] = pos;
        if (l == 2) lmn[1] = pos;
        if (p == 1) lmn[2] = pos;
        if (p == 2) lmn[3] = pos;
    }

    __shared__ int sF[6][NTHREADS];
    __shared__ int sB[4][NTHREADS];
    #pragma unroll
    for (int i = 0; i < 6; ++i) sF[i][tid] = lmx[i];
    #pragma unroll
    for (int i = 0; i < 4; ++i) sB[i][tid] = lmn[i];
    __syncthreads();
    // Hillis-Steele: inclusive max-scan (fwd) + inclusive min-scan (bwd)
    for (int st = 1; st < NTHREADS; st <<= 1) {
        int vF[6], vB[4];
        const bool doF = (tid >= st);
        const bool doB = (tid + st < NTHREADS);
        if (doF) {
            #pragma unroll
            for (int i = 0; i < 6; ++i) vF[i] = max(sF[i][tid], sF[i][tid - st]);
        }
        if (doB) {
            #pragma unroll
            for (int i = 0; i < 4; ++i) vB[i] = min(sB[i][tid], sB[i][tid + st]);
        }
        __syncthreads();
        if (doF) {
            #pragma unroll
            for (int i = 0; i < 6; ++i) sF[i][tid] = vF[i];
        }
        if (doB) {
            #pragma unroll
            for (int i = 0; i < 4; ++i) sB[i][tid] = vB[i];
        }
        __syncthreads();
    }

    const ChunkIn cin = ins[chunkId];
    int exF[6], exB[4];
    #pragma unroll
    for (int i = 0; i < 6; ++i) exF[i] = (tid > 0) ? max(cin.inLast[i], sF[i][tid - 1]) : cin.inLast[i];
    #pragma unroll
    for (int i = 0; i < 4; ++i) exB[i] = (tid < NTHREADS - 1) ? min(cin.inNext[i], sB[i][tid + 1]) : cin.inNext[i];

    // backward local walk: inclusive next-distances, clamped to 255, packed
    unsigned nd[PER_THREAD];
    {
        int n1 = exB[0], n2 = exB[1], n3 = exB[2], n4 = exB[3];
        #pragma unroll
        for (int j = PER_THREAD - 1; j >= 0; --j) {
            const int pos = posBase + j;
            const int l = lab[j], p = prd[j];
            if (l == 1) n1 = pos;
            if (l == 2) n2 = pos;
            if (p == 1) n3 = pos;
            if (p == 2) n4 = pos;
            const int d1 = min(n1 - pos, 255);
            const int d2 = min(n2 - pos, 255);
            const int d3 = min(n3 - pos, 255);
            const int d4 = min(n4 - pos, 255);
            nd[j] = (unsigned)d1 | ((unsigned)d2 << 8) | ((unsigned)d3 << 16) | ((unsigned)d4 << 24);
        }
    }

    const int aT1 = anyFlags[4*seq+0], aT2 = anyFlags[4*seq+1];
    const int aP1 = anyFlags[4*seq+2], aP2 = anyFlags[4*seq+3];

    double sumAdj = 0.0;
    int vcount = 0;
    {
        int lT1 = exF[0], lT2 = exF[1], lP1 = exF[2], lP2 = exF[3], lV1 = exF[4], lV2 = exF[5];
        #pragma unroll
        for (int j = 0; j < PER_THREAD; ++j) {
            const int pos = posBase + j;
            const int l = lab[j], p = prd[j];
            const bool valid = (l >= 0);
            // FSM state BEFORE this element (exclusive)
            const int tm = (lT2 > lT1) ? 1 : 0;
            const int pm = (lV2 > lV1) ? 1 : 0;
            float m = 1.0f;
            if (valid && p == 1 && pm == 0) m *= 100.0f;   // ITP
            if (valid && p == 2 && pm == 1) m *= 100.0f;   // ITP
            if (l == 1 && tm == 1 && p == 1) m *= 0.1f;
            if (l == 2 && tm == 0 && p == 2) m *= 0.1f;
            // update (distances are inclusive)
            if (l == 1) lT1 = pos;
            if (l == 2) lT2 = pos;
            if (p == 1) lP1 = pos;
            if (p == 2) lP2 = pos;
            if (valid && p == 1) lV1 = pos;
            if (valid && p == 2) lV2 = pos;

            const int dpT1 = (lT1 >= 0) ? min(pos - lT1, 255) : 255;
            const int dpT2 = (lT2 >= 0) ? min(pos - lT2, 255) : 255;
            const int dpP1 = (lP1 >= 0) ? min(pos - lP1, 255) : 255;
            const int dpP2 = (lP2 >= 0) ? min(pos - lP2, 255) : 255;
            const unsigned ndj = nd[j];
            const int d2t1 = min(dpT1, (int)(ndj & 255u));
            const int d2t2 = min(dpT2, (int)((ndj >> 8) & 255u));
            const int d2p1 = min(dpP1, (int)((ndj >> 16) & 255u));
            const int d2p2 = min(dpP2, (int)((ndj >> 24) & 255u));

            if (p == 1) m *= aT1 ? ((d2t1 == 0) ? 0.1f : ((d2t1 <= 5) ? (0.1f + (float)d2t1 / 5.0f * 0.9f) : 10.0f)) : 20.0f;
            if (p == 2) m *= aT2 ? ((d2t2 == 0) ? 0.1f : ((d2t2 <= 5) ? (0.1f + (float)d2t2 / 5.0f * 0.9f) : 10.0f)) : 20.0f;
            if (l == 1) m *= aP1 ? ((d2p1 > 5) ? fminf(2.0f + (float)(d2p1 - 5) * 0.3f, 8.0f) : 1.0f) : 5.0f;
            if (l == 2) m *= aP2 ? ((d2p2 > 5) ? fminf(2.0f + (float)(d2p2 - 5) * 0.3f, 8.0f) : 1.0f) : 5.0f;

            sumAdj += (double)(ce[j] * m);
            vcount += valid ? 1 : 0;
        }
    }

    __shared__ double rA[NTHREADS];
    __shared__ double rV[NTHREADS];
    rA[tid] = sumAdj;
    rV[tid] = (double)vcount;
    __syncthreads();
    for (int st = NTHREADS / 2; st > 0; st >>= 1) {
        if (tid < st) { rA[tid] += rA[tid + st]; rV[tid] += rV[tid + st]; }
        __syncthreads();
    }
    if (tid == 0) {
        partials[2 * chunkId + 0] = rA[0];
        partials[2 * chunkId + 1] = rV[0];
    }
}

__global__ __launch_bounds__(NTHREADS) void k4_final(const double* __restrict__ partials,
                                                     float* __restrict__ out) {
    const int tid = threadIdx.x;
    double sA = 0.0, sV = 0.0;
    for (int i = tid; i < NCHUNK; i += NTHREADS) {
        sA += partials[2 * i + 0];
        sV += partials[2 * i + 1];
    }
    __shared__ double rA[NTHREADS];
    __shared__ double rV[NTHREADS];
    rA[tid] = sA; rV[tid] = sV;
    __syncthreads();
    for (int st = NTHREADS / 2; st > 0; st >>= 1) {
        if (tid < st) { rA[tid] += rA[tid + st]; rV[tid] += rV[tid + st]; }
        __syncthreads();
    }
    if (tid == 0) out[0] = (float)(rA[0] / fmax(rV[0], 1.0));
}

extern "C" void kernel_launch(void* const* d_in, const int* in_sizes, int n_in,
                              void* d_out, int out_size, void* d_ws, size_t ws_size,
                              hipStream_t stream) {
    const float* logits = (const float*)d_in[0];
    const int*   labels = (const int*)d_in[1];
    float* out = (float*)d_out;
    char* ws = (char*)d_ws;

    ChunkSum* sums   = (ChunkSum*)(ws + WS_SUMS);
    ChunkIn*  ins    = (ChunkIn*)(ws + WS_INS);
    int*      flags  = (int*)(ws + WS_FLAGS);
    double*   parts  = (double*)(ws + WS_PART);

    k1_summ<<<NCHUNK, NTHREADS, 0, stream>>>(logits, labels, sums);
    k2_combine<<<1, 64, 0, stream>>>(sums, ins, flags);
    k3_main<<<NCHUNK, NTHREADS, 0, stream>>>(logits, labels, ins, flags, parts);
    k4_final<<<1, NTHREADS, 0, stream>>>(parts, out);
}